// Round 2
// baseline (125.626 us; speedup 1.0000x reference)
//
#include <hip/hip_runtime.h>

// InterpolationBlock1D_Lin: out[e][k] = sf[e][0][k]*nodal[conn[c][0]-1] + sf[e][1][k]*nodal[conn[c][1]-1]
// Memory-bound streaming: 256 MB sf read + 128 MB out write + small gathers.

__global__ __launch_bounds__(256) void interp1d_kernel(
    const int*    __restrict__ cell_id,   // [N_EVAL]
    const float*  __restrict__ nodal,     // [N_NODES]
    const float4* __restrict__ sf,        // [N_EVAL][2][16] -> 8 float4 per eval
    const int2*   __restrict__ conn,      // [N_CELLS][2]
    float4*       __restrict__ out,       // [N_EVAL][16] -> 4 float4 per eval
    int n_eval)
{
    int e = blockIdx.x * blockDim.x + threadIdx.x;
    if (e >= n_eval) return;

    int c = cell_id[e];
    int2 nn = conn[c];               // 1-based node ids
    float n1 = nodal[nn.x - 1];
    float n2 = nodal[nn.y - 1];

    const float4* s = sf + (size_t)e * 8;   // s[0..3] = sf[e][0][:], s[4..7] = sf[e][1][:]
    float4* o = out + (size_t)e * 4;

#pragma unroll
    for (int q = 0; q < 4; ++q) {
        float4 a = s[q];
        float4 b = s[q + 4];
        float4 r;
        r.x = fmaf(a.x, n1, b.x * n2);
        r.y = fmaf(a.y, n1, b.y * n2);
        r.z = fmaf(a.z, n1, b.z * n2);
        r.w = fmaf(a.w, n1, b.w * n2);
        o[q] = r;
    }
}

extern "C" void kernel_launch(void* const* d_in, const int* in_sizes, int n_in,
                              void* d_out, int out_size, void* d_ws, size_t ws_size,
                              hipStream_t stream) {
    // Input order from setup_inputs(): x, cell_id, nodal_values, shape_functions, connectivity
    const int*    cell_id = (const int*)d_in[1];
    const float*  nodal   = (const float*)d_in[2];
    const float4* sf      = (const float4*)d_in[3];
    const int2*   conn    = (const int2*)d_in[4];
    float4*       out     = (float4*)d_out;

    int n_eval = in_sizes[1];

    int block = 256;
    int grid = (n_eval + block - 1) / block;
    interp1d_kernel<<<grid, block, 0, stream>>>(cell_id, nodal, sf, conn, out, n_eval);
}

// Round 3
// 103.985 us; speedup vs baseline: 1.2081x; 1.2081x over previous
//
#include <hip/hip_runtime.h>

// InterpolationBlock1D_Lin: out[e][k] = sf[e][0][k]*n1[e] + sf[e][1][k]*n2[e]
// n1/n2 gathered via cell_id -> connectivity -> nodal_values.
//
// Layout fix vs round 2: one thread per OUTPUT float4 (4 threads per eval),
// so stores are lane-contiguous (16B stride) and sf loads drop from 64 to 16
// transactions per wave instruction. sf/out are streamed nontemporally.

typedef float f32x4 __attribute__((ext_vector_type(4)));

__global__ __launch_bounds__(256) void interp1d_kernel(
    const int*   __restrict__ cell_id,   // [N_EVAL]
    const float* __restrict__ nodal,     // [N_NODES]
    const f32x4* __restrict__ sf,        // [N_EVAL][2][16] -> 8 f32x4 per eval
    const int2*  __restrict__ conn,      // [N_CELLS][2]
    f32x4*       __restrict__ out,       // [N_EVAL][16] -> 4 f32x4 per eval
    int n_out4)                          // N_EVAL*4
{
    int i = blockIdx.x * blockDim.x + threadIdx.x;
    if (i >= n_out4) return;

    int e = i >> 2;          // eval point (shared by 4 consecutive lanes -> broadcast loads)
    int j = i & 3;           // which float4 of the 16-wide output row

    int c = cell_id[e];
    int2 nn = conn[c];       // 1-based node ids
    float n1 = nodal[nn.x - 1];
    float n2 = nodal[nn.y - 1];

    const f32x4* s = sf + ((size_t)e * 8 + j);
    f32x4 a = __builtin_nontemporal_load(s);       // sf[e][0][4j..4j+3]
    f32x4 b = __builtin_nontemporal_load(s + 4);   // sf[e][1][4j..4j+3]

    f32x4 r = a * n1 + b * n2;

    __builtin_nontemporal_store(r, out + i);
}

extern "C" void kernel_launch(void* const* d_in, const int* in_sizes, int n_in,
                              void* d_out, int out_size, void* d_ws, size_t ws_size,
                              hipStream_t stream) {
    // Input order from setup_inputs(): x, cell_id, nodal_values, shape_functions, connectivity
    const int*   cell_id = (const int*)d_in[1];
    const float* nodal   = (const float*)d_in[2];
    const f32x4* sf      = (const f32x4*)d_in[3];
    const int2*  conn    = (const int2*)d_in[4];
    f32x4*       out     = (f32x4*)d_out;

    int n_eval = in_sizes[1];
    int n_out4 = n_eval * 4;

    int block = 256;
    int grid = (n_out4 + block - 1) / block;
    interp1d_kernel<<<grid, block, 0, stream>>>(cell_id, nodal, sf, conn, out, n_out4);
}